// Round 14
// baseline (3289.160 us; speedup 1.0000x reference)
//
#include <hip/hip_runtime.h>
#include <hip/hip_bf16.h>
#include <cmath>
#include <cstdint>

// ---------------------------------------------------------------------------
// Stacked 2-layer Elman RNN, bf16 hi/lo-split MFMA (3-pass) everywhere.
//   splits: weights + gathered embedding + initial hidden -> bf16 hi/lo
//   A0 = embsplit @ Wx0^T + bh0                         (MFMA GEMM)
//   ONE persistent cooperative kernel (64 blocks x 512 thr), flag-synced:
//     blocks 0-31  (layer 0): h0[t] = tanh(A0[t] + h0[t-1] @ Wh0^T)
//     blocks 32-63 (layer 1): h1[t] = tanh(h0[t]@Wx1^T + h1[t-1]@Wh1^T + bh1)
//     32 output columns per block; W-hi slices LDS-resident (swizzled),
//     W-lo streamed from L2; 4-way split accumulation (chains of 24/48).
//   R14 delta vs R13: 32 participants per barrier instead of 64 (halves the
//   fetch_add queue + straggler width), 8-wave blocks, 4-chain ILP.
//   h publish: packed u64 agent-scope relaxed atomic stores (write-through);
//   counters fetch_add after __syncthreads drain; relaxed throttled polls.
//   h_final = hi+lo of t=69;
//   logits = H1split @ Wy^T + by  (separate GEMM, XCD-aware bijective remap)
// ---------------------------------------------------------------------------

using u16 = unsigned short;
using u32 = unsigned int;
using u64 = unsigned long long;
typedef __attribute__((ext_vector_type(8))) short short8;  // bf16x8 MFMA frag
typedef __attribute__((ext_vector_type(4))) float f32x4;

#define MFMA_BF16(a, b, c) __builtin_amdgcn_mfma_f32_16x16x32_bf16((a), (b), (c), 0, 0, 0)

__device__ __forceinline__ u16 bf16_rne(float x) {
    u32 u = __float_as_uint(x);
    u32 r = u + 0x7FFFu + ((u >> 16) & 1u);
    return (u16)(r >> 16);
}
__device__ __forceinline__ float bf16_f(u16 h) {
    return __uint_as_float(((u32)h) << 16);
}
__device__ __forceinline__ void split2(float x, u16& hi, u16& lo) {
    hi = bf16_rne(x);
    lo = bf16_rne(x - bf16_f(hi));
}
__device__ __forceinline__ u64 pack4(u16 a, u16 b, u16 c, u16 d) {
    return (u64)a | ((u64)b << 16) | ((u64)c << 32) | ((u64)d << 48);
}

// ---- cross-workgroup sync (R7 semantics; throttled polls) -----------------
__device__ __forceinline__ void wait_count(int* f, int target) {
    if (threadIdx.x == 0) {
        while (__hip_atomic_load(f, __ATOMIC_RELAXED, __HIP_MEMORY_SCOPE_AGENT) < target)
            __builtin_amdgcn_s_sleep(16);
    }
    __syncthreads();
}
__device__ __forceinline__ void wait_count2(int* f0, int tgt0, int* f1, int tgt1) {
    if (threadIdx.x == 0) {
        for (;;) {
            int v0 = __hip_atomic_load(f0, __ATOMIC_RELAXED, __HIP_MEMORY_SCOPE_AGENT);
            int v1 = __hip_atomic_load(f1, __ATOMIC_RELAXED, __HIP_MEMORY_SCOPE_AGENT);
            if (v0 >= tgt0 && v1 >= tgt1) break;
            __builtin_amdgcn_s_sleep(16);
        }
    }
    __syncthreads();
}
__device__ __forceinline__ void signal_done(int* f) {
    __syncthreads();   // vmcnt(0): write-through h-stores drained
    if (threadIdx.x == 0)
        __hip_atomic_fetch_add(f, 1, __ATOMIC_RELAXED, __HIP_MEMORY_SCOPE_AGENT);
}

// ---------------- generic split: fp32 -> bf16 hi/lo (float4 per thread) -----
__global__ __launch_bounds__(256) void split_kernel(
    const float* __restrict__ src, u16* __restrict__ hi, u16* __restrict__ lo, int n4)
{
    int g = blockIdx.x * 256 + threadIdx.x;
    if (g >= n4) return;
    float4 v = *reinterpret_cast<const float4*>(src + (size_t)g * 4);
    u16 h0,h1,h2,h3,l0,l1,l2,l3;
    split2(v.x,h0,l0); split2(v.y,h1,l1); split2(v.z,h2,l2); split2(v.w,h3,l3);
    ushort4 H = {h0,h1,h2,h3}, L = {l0,l1,l2,l3};
    *reinterpret_cast<ushort4*>(hi + (size_t)g * 4) = H;
    *reinterpret_cast<ushort4*>(lo + (size_t)g * 4) = L;
}

// ---------------- fused gather(emb, idx) + split:  out [M][512] -------------
__global__ __launch_bounds__(256) void gather_split_kernel(
    const float* __restrict__ emb, const int* __restrict__ idx,
    u16* __restrict__ hi, u16* __restrict__ lo, int n4)
{
    int g = blockIdx.x * 256 + threadIdx.x;    // M*512/4 = 573440
    if (g >= n4) return;
    int m  = g >> 7;
    int c4 = g & 127;
    const float* src = emb + (size_t)idx[m] * 512 + c4 * 4;
    float4 v = *reinterpret_cast<const float4*>(src);
    u16 h0,h1,h2,h3,l0,l1,l2,l3;
    split2(v.x,h0,l0); split2(v.y,h1,l1); split2(v.z,h2,l2); split2(v.w,h3,l3);
    ushort4 H = {h0,h1,h2,h3}, L = {l0,l1,l2,l3};
    size_t o = (size_t)m * 512 + c4 * 4;
    *reinterpret_cast<ushort4*>(hi + o) = H;
    *reinterpret_cast<ushort4*>(lo + o) = L;
}

// ---------------- bf16-split MFMA GEMM tile body (device) ------------------
__device__ __forceinline__ void gemm_tile(
    const u16* __restrict__ Ah, const u16* __restrict__ Al,
    const u16* __restrict__ Bh, const u16* __restrict__ Bl,
    const float* __restrict__ bias, float* __restrict__ C,
    int N, int K, int m0, int n0,
    u16* sAh, u16* sAl, u16* sBh, u16* sBl)
{
    const int tid  = threadIdx.x;
    const int lane = tid & 63;
    const int w    = tid >> 6;
    const int wr   = w >> 1, wc = w & 1;

    f32x4 acc[4][4];
    #pragma unroll
    for (int i = 0; i < 4; ++i)
        #pragma unroll
        for (int j = 0; j < 4; ++j) acc[i][j] = 0.0f;

    for (int k0 = 0; k0 < K; k0 += 32) {
        #pragma unroll
        for (int r = 0; r < 2; ++r) {
            int s   = r * 256 + tid;
            int row = s >> 2, q = s & 3;
            int gq  = q ^ (row & 3);
            int l16 = row * 32 + q * 8;
            size_t ga = (size_t)(m0 + row) * K + k0 + gq * 8;
            int brow = n0 + row; if (brow >= N) brow = N - 1;
            size_t gb = (size_t)brow * K + k0 + gq * 8;
            *reinterpret_cast<int4*>(sAh + l16) = *reinterpret_cast<const int4*>(Ah + ga);
            *reinterpret_cast<int4*>(sAl + l16) = *reinterpret_cast<const int4*>(Al + ga);
            *reinterpret_cast<int4*>(sBh + l16) = *reinterpret_cast<const int4*>(Bh + gb);
            *reinterpret_cast<int4*>(sBl + l16) = *reinterpret_cast<const int4*>(Bl + gb);
        }
        __syncthreads();

        const int q4 = lane >> 4;
        short8 afh[4], afl[4];
        #pragma unroll
        for (int i = 0; i < 4; ++i) {
            int ra  = wr * 64 + i * 16 + (lane & 15);
            int off = ra * 32 + (q4 ^ (ra & 3)) * 8;
            afh[i] = *reinterpret_cast<const short8*>(sAh + off);
            afl[i] = *reinterpret_cast<const short8*>(sAl + off);
        }
        #pragma unroll
        for (int j = 0; j < 4; ++j) {
            int rb  = wc * 64 + j * 16 + (lane & 15);
            int off = rb * 32 + (q4 ^ (rb & 3)) * 8;
            short8 bfh = *reinterpret_cast<const short8*>(sBh + off);
            short8 bfl = *reinterpret_cast<const short8*>(sBl + off);
            #pragma unroll
            for (int i = 0; i < 4; ++i) {
                acc[i][j] = MFMA_BF16(afh[i], bfh, acc[i][j]);
                acc[i][j] = MFMA_BF16(afh[i], bfl, acc[i][j]);
                acc[i][j] = MFMA_BF16(afl[i], bfh, acc[i][j]);
            }
        }
        __syncthreads();
    }

    #pragma unroll
    for (int j = 0; j < 4; ++j) {
        int n = n0 + wc * 64 + j * 16 + (lane & 15);
        if (n < N) {
            float bv = bias[n];
            #pragma unroll
            for (int i = 0; i < 4; ++i) {
                #pragma unroll
                for (int r = 0; r < 4; ++r) {
                    int m = m0 + wr * 64 + i * 16 + (lane >> 4) * 4 + r;
                    C[(size_t)m * N + n] = acc[i][j][r] + bv;
                }
            }
        }
    }
}

// ---------------- standalone GEMM (A0 prologue) ----------------------------
__global__ __launch_bounds__(256) void gemm_mfma(
    const u16* __restrict__ Ah, const u16* __restrict__ Al,
    const u16* __restrict__ Bh, const u16* __restrict__ Bl,
    const float* __restrict__ bias, float* __restrict__ C,
    int M, int N, int K)
{
    __shared__ u16 sAh[128*32], sAl[128*32], sBh[128*32], sBl[128*32];
    gemm_tile(Ah, Al, Bh, Bl, bias, C, N, K,
              blockIdx.y * 128, blockIdx.x * 128, sAh, sAl, sBh, sBl);
}

// ---------------- logits GEMM with XCD-aware bijective block remap ---------
__global__ __launch_bounds__(256) void gemm_mfma_swz(
    const u16* __restrict__ Ah, const u16* __restrict__ Al,
    const u16* __restrict__ Bh, const u16* __restrict__ Bl,
    const float* __restrict__ bias, float* __restrict__ C,
    int M, int N, int K)
{
    __shared__ u16 sAh[128*32], sAl[128*32], sBh[128*32], sBl[128*32];
    const int NTN = 79;                       // ceil(10000/128)
    const int nwg = 35 * 79;                  // 2765
    const int q = nwg / 8, r = nwg % 8;       // 345, 5
    int orig = (int)blockIdx.x;
    int xcd  = orig % 8;
    int idx  = orig / 8;
    int wg   = (xcd < r) ? (xcd * (q + 1) + idx)
                         : (r * (q + 1) + (xcd - r) * q + idx);
    int mb = wg / NTN, nb = wg % NTN;
    gemm_tile(Ah, Al, Bh, Bl, bias, C, N, K,
              mb * 128, nb * 128, sAh, sAl, sBh, sBl);
}

// ---- per-chain MFMA step macros (3-pass: ah*bh + ah*bl + al*bh) -----------
// Layer 0: bh from LDS (64KB, swizzled), bl from L2 (Wh0l).
#define L0C(accv, ktv) { \
    int kt_ = (ktv); \
    short8 ah_ = *reinterpret_cast<const short8*>(hph + (size_t)arow * 1024 + kt_ * 32 + q4 * 8); \
    short8 al_ = *reinterpret_cast<const short8*>(hpl + (size_t)arow * 1024 + kt_ * 32 + q4 * 8); \
    int slot_ = (kt_ * 4 + q4) ^ (cl & 7); \
    short8 bh_ = *reinterpret_cast<const short8*>(sW + cl * 1024 + slot_ * 8); \
    short8 bl_ = *reinterpret_cast<const short8*>(Wh0l + (size_t)(n0 + cl) * 1024 + kt_ * 32 + q4 * 8); \
    accv = MFMA_BF16(ah_, bh_, accv); \
    accv = MFMA_BF16(ah_, bl_, accv); \
    accv = MFMA_BF16(al_, bh_, accv); }

// Layer 1: bh from LDS [Wx1|Wh1] (128KB, swizzled), bl from L2.
#define L1C(accv, ktv, sbase, ph, pl, BlPtr) { \
    int kt_ = (ktv); \
    short8 ah_ = *reinterpret_cast<const short8*>((ph) + (size_t)arow * 1024 + kt_ * 32 + q4 * 8); \
    short8 al_ = *reinterpret_cast<const short8*>((pl) + (size_t)arow * 1024 + kt_ * 32 + q4 * 8); \
    int slot_ = (((sbase) + kt_) * 4 + q4) ^ (cl & 7); \
    short8 bh_ = *reinterpret_cast<const short8*>(sW + cl * 2048 + slot_ * 8); \
    short8 bl_ = *reinterpret_cast<const short8*>((BlPtr) + (size_t)(n0 + cl) * 1024 + kt_ * 32 + q4 * 8); \
    accv = MFMA_BF16(ah_, bh_, accv); \
    accv = MFMA_BF16(ah_, bl_, accv); \
    accv = MFMA_BF16(al_, bh_, accv); }

// ---------------- persistent recurrence kernel (32+32 x 512thr) ------------
// flags[0..69]  = # layer-0 blocks done with h0[t]   (target 32)
// flags[70..139]= # layer-1 blocks done with h1[t]   (target 32)
__global__ __launch_bounds__(512, 1) void rnn_persist4(
    const float* __restrict__ A0,
    const u16* __restrict__ hs0h, const u16* __restrict__ hs0l,
    const u16* __restrict__ hs1h, const u16* __restrict__ hs1l,
    u16* __restrict__ H0h, u16* __restrict__ H0l,
    u16* __restrict__ H1h, u16* __restrict__ H1l,
    const u16* __restrict__ Wh0h, const u16* __restrict__ Wh0l,
    const u16* __restrict__ Wx1h, const u16* __restrict__ Wx1l,
    const u16* __restrict__ Wh1h, const u16* __restrict__ Wh1l,
    const float* __restrict__ bh1, int* flags)
{
    __shared__ u16 sW[65536];            // 128 KiB W-hi (L0 uses 64 KiB)
    __shared__ u16 sStageH[64 * 36];     // h-tile staging, bf16 hi
    __shared__ u16 sStageL[64 * 36];     // h-tile staging, bf16 lo
    const int tid   = threadIdx.x;
    const int lane  = tid & 63;
    const int w     = tid >> 6;          // 0..7
    const int wr    = w >> 1;            // row-frag 0..3 (rows wr*16..+16)
    const int wc    = w & 1;             // col-frag 0..1
    const int layer = (int)(blockIdx.x >> 5);
    const int bidx  = (int)(blockIdx.x & 31);
    const int n0    = bidx * 32;
    const int rb    = lane & 15;
    const int q4    = lane >> 4;
    const int arow  = wr * 16 + rb;      // A-operand row (h row)
    const int cl    = wc * 16 + rb;      // output col within block
    const size_t BH = 65536;
    const int srow  = tid >> 3;          // publish: row 0..63
    const int sc4   = (tid & 7) * 4;     // publish: col group 0,4..28

    // ---- stage W-hi slice into LDS, XOR-swizzled on 16B quads ----
    if (layer == 0) {
        // 32 cols x 1024 k = 32768 u16 = 4096 int4, 8 rounds x 512 thr
        for (int i = 0; i < 8; ++i) {
            int s    = i * 512 + tid;
            int c    = s >> 7;
            int g    = s & 127;
            int slot = g ^ (c & 7);
            *reinterpret_cast<int4*>(sW + c * 1024 + slot * 8) =
                *reinterpret_cast<const int4*>(Wh0h + (size_t)(n0 + c) * 1024 + g * 8);
        }
    } else {
        // 32 cols x 2048 k ([Wx1|Wh1]) = 65536 u16 = 8192 int4, 16 rounds
        for (int i = 0; i < 16; ++i) {
            int s    = i * 512 + tid;
            int c    = s >> 8;
            int g    = s & 255;
            int slot = g ^ (c & 7);
            const u16* src = (g < 128)
                ? Wx1h + (size_t)(n0 + c) * 1024 + g * 8
                : Wh1h + (size_t)(n0 + c) * 1024 + (g - 128) * 8;
            *reinterpret_cast<int4*>(sW + c * 2048 + slot * 8) =
                *reinterpret_cast<const int4*>(src);
        }
    }
    __syncthreads();

    if (layer == 0) {
        for (int t = 0; t < 70; ++t) {
            if (t > 0) wait_count(flags + (t - 1), 32);
            const u16* hph = t ? H0h + (size_t)(t - 1) * BH : hs0h;
            const u16* hpl = t ? H0l + (size_t)(t - 1) * BH : hs0l;
            f32x4 c0 = {0.f,0.f,0.f,0.f}, c1 = {0.f,0.f,0.f,0.f};
            f32x4 c2 = {0.f,0.f,0.f,0.f}, c3 = {0.f,0.f,0.f,0.f};
            #pragma unroll
            for (int i = 0; i < 8; ++i) {
                L0C(c0, i);
                L0C(c1, 8 + i);
                L0C(c2, 16 + i);
                L0C(c3, 24 + i);
            }
            f32x4 acc = (c0 + c1) + (c2 + c3);
            #pragma unroll
            for (int r = 0; r < 4; ++r) {
                int m = wr * 16 + q4 * 4 + r;
                size_t o = (size_t)t * BH + (size_t)m * 1024 + n0 + cl;
                float hv = tanhf(acc[r] + A0[o]);
                u16 hi, lo; split2(hv, hi, lo);
                sStageH[m * 36 + cl] = hi;
                sStageL[m * 36 + cl] = lo;
            }
            __syncthreads();
            {
                ushort4 hv = *reinterpret_cast<const ushort4*>(sStageH + srow * 36 + sc4);
                ushort4 lv = *reinterpret_cast<const ushort4*>(sStageL + srow * 36 + sc4);
                size_t o64 = ((size_t)t * BH + (size_t)srow * 1024 + n0 + sc4) >> 2;
                __hip_atomic_store((u64*)H0h + o64, pack4(hv.x,hv.y,hv.z,hv.w),
                                   __ATOMIC_RELAXED, __HIP_MEMORY_SCOPE_AGENT);
                __hip_atomic_store((u64*)H0l + o64, pack4(lv.x,lv.y,lv.z,lv.w),
                                   __ATOMIC_RELAXED, __HIP_MEMORY_SCOPE_AGENT);
            }
            signal_done(flags + t);
        }
    } else {
        for (int t = 0; t < 70; ++t) {
            if (t > 0) wait_count2(flags + t, 32, flags + 70 + (t - 1), 32);
            else       wait_count(flags + t, 32);
            const u16* h0h  = H0h + (size_t)t * BH;
            const u16* h0l  = H0l + (size_t)t * BH;
            const u16* h1ph = t ? H1h + (size_t)(t - 1) * BH : hs1h;
            const u16* h1pl = t ? H1l + (size_t)(t - 1) * BH : hs1l;
            f32x4 c0 = {0.f,0.f,0.f,0.f}, c1 = {0.f,0.f,0.f,0.f};
            f32x4 c2 = {0.f,0.f,0.f,0.f}, c3 = {0.f,0.f,0.f,0.f};
            #pragma unroll
            for (int i = 0; i < 16; ++i) {
                L1C(c0, i,       0,  h0h,  h0l,  Wx1l);
                L1C(c1, 16 + i,  0,  h0h,  h0l,  Wx1l);
                L1C(c2, i,       32, h1ph, h1pl, Wh1l);
                L1C(c3, 16 + i,  32, h1ph, h1pl, Wh1l);
            }
            f32x4 acc = (c0 + c1) + (c2 + c3);
            const int n = n0 + cl;
            #pragma unroll
            for (int r = 0; r < 4; ++r) {
                int m = wr * 16 + q4 * 4 + r;
                float hv = tanhf(acc[r] + bh1[n]);
                u16 hi, lo; split2(hv, hi, lo);
                sStageH[m * 36 + cl] = hi;
                sStageL[m * 36 + cl] = lo;
            }
            __syncthreads();
            {
                ushort4 hv = *reinterpret_cast<const ushort4*>(sStageH + srow * 36 + sc4);
                ushort4 lv = *reinterpret_cast<const ushort4*>(sStageL + srow * 36 + sc4);
                size_t o64 = ((size_t)t * BH + (size_t)srow * 1024 + n0 + sc4) >> 2;
                __hip_atomic_store((u64*)H1h + o64, pack4(hv.x,hv.y,hv.z,hv.w),
                                   __ATOMIC_RELAXED, __HIP_MEMORY_SCOPE_AGENT);
                __hip_atomic_store((u64*)H1l + o64, pack4(lv.x,lv.y,lv.z,lv.w),
                                   __ATOMIC_RELAXED, __HIP_MEMORY_SCOPE_AGENT);
            }
            signal_done(flags + 70 + t);
        }
    }
}

// ---------------- h_final tail (hi+lo reconstruction) ----------------------
__global__ __launch_bounds__(256) void hfinal_kernel(
    const u16* __restrict__ H0h, const u16* __restrict__ H0l,
    const u16* __restrict__ H1h, const u16* __restrict__ H1l,
    float* __restrict__ outp)
{
    int i = blockIdx.x * 256 + threadIdx.x;
    outp[i]         = bf16_f(H0h[i]) + bf16_f(H0l[i]);
    outp[65536 + i] = bf16_f(H1h[i]) + bf16_f(H1l[i]);
}

extern "C" void kernel_launch(void* const* d_in, const int* in_sizes, int n_in,
                              void* d_out, int out_size, void* d_ws, size_t ws_size,
                              hipStream_t stream)
{
    const int*   inputs = (const int*)  d_in[0];
    const float* hidden = (const float*)d_in[1];
    const float* embW   = (const float*)d_in[2];
    const float* Wx0    = (const float*)d_in[3];
    const float* Wx1    = (const float*)d_in[4];
    const float* Wh0    = (const float*)d_in[5];
    const float* bh0    = (const float*)d_in[6];
    const float* Wh1    = (const float*)d_in[7];
    const float* bh1    = (const float*)d_in[8];
    const float* Wy     = (const float*)d_in[9];
    const float* by     = (const float*)d_in[10];
    float* out = (float*)d_out;

    const int T = 70, B = 64, V = 10000, E = 512, H = 1024;
    const int M = T * B;
    const size_t MH = (size_t)M * H;
    const size_t BH = (size_t)B * H;

    char* wsb = (char*)d_ws;
    u16*   Wyh  = (u16*)(wsb);
    u16*   Wyl  = Wyh + (size_t)V * H;
    float* buf0 = (float*)(wsb + 40960000);
    u16*   H0h  = (u16*)(wsb + 59310080);
    u16*   H0l  = H0h + MH;
    u16*   H1h  = H0l + MH;
    u16*   H1l  = H1h + MH;
    u16*   Wx0h = H1l + MH;
    u16*   Wx0l = Wx0h + (size_t)H * E;
    u16*   Wx1h = Wx0l + (size_t)H * E;
    u16*   Wx1l = Wx1h + (size_t)H * H;
    u16*   Wh0h = Wx1l + (size_t)H * H;
    u16*   Wh0l = Wh0h + (size_t)H * H;
    u16*   Wh1h = Wh0l + (size_t)H * H;
    u16*   Wh1l = Wh1h + (size_t)H * H;
    u16*   hs0h = Wh1l + (size_t)H * H;
    u16*   hs0l = hs0h + BH;
    u16*   hs1h = hs0l + BH;
    u16*   hs1l = hs1h + BH;

    // d_out aliased scratch: gathered emb splits (dead after A0 GEMM) and
    // sync flags (dead after persist; overwritten by logits afterwards).
    u16*   Agh   = (u16*)((char*)d_out + 20971520);
    u16*   Agl   = Agh + (size_t)M * E;
    int*   flags = (int*)((char*)d_out + 104857600);   // +100 MB, 140 ints

    dim3 blk(256);

    hipMemsetAsync(flags, 0, 140 * sizeof(int), stream);

    split_kernel<<<dim3((H*E)/1024), blk, 0, stream>>>(Wx0, Wx0h, Wx0l, (H*E)/4);
    split_kernel<<<dim3((H*H)/1024), blk, 0, stream>>>(Wx1, Wx1h, Wx1l, (H*H)/4);
    split_kernel<<<dim3((H*H)/1024), blk, 0, stream>>>(Wh0, Wh0h, Wh0l, (H*H)/4);
    split_kernel<<<dim3((H*H)/1024), blk, 0, stream>>>(Wh1, Wh1h, Wh1l, (H*H)/4);
    split_kernel<<<dim3((V*H)/1024), blk, 0, stream>>>(Wy,  Wyh,  Wyl,  (V*H)/4);
    split_kernel<<<dim3(64), blk, 0, stream>>>(hidden,      hs0h, hs0l, (int)BH/4);
    split_kernel<<<dim3(64), blk, 0, stream>>>(hidden + BH, hs1h, hs1l, (int)BH/4);
    gather_split_kernel<<<dim3((M*E)/1024), blk, 0, stream>>>(embW, inputs, Agh, Agl, (M*E)/4);

    // A0 = embsplit @ Wx0^T + bh0
    gemm_mfma<<<dim3(H/128, M/128), blk, 0, stream>>>(
        Agh, Agl, Wx0h, Wx0l, bh0, buf0, M, H, E);

    // persistent recurrence: 64 blocks x 512 threads, flag-synced
    {
        const float* A0p = buf0;
        void* args[] = {
            (void*)&A0p,
            (void*)&hs0h, (void*)&hs0l, (void*)&hs1h, (void*)&hs1l,
            (void*)&H0h,  (void*)&H0l,  (void*)&H1h,  (void*)&H1l,
            (void*)&Wh0h, (void*)&Wh0l, (void*)&Wx1h, (void*)&Wx1l,
            (void*)&Wh1h, (void*)&Wh1l, (void*)&bh1, (void*)&flags
        };
        hipLaunchCooperativeKernel(reinterpret_cast<void*>(rnn_persist4),
                                   dim3(64), dim3(512), args, 0, stream);
    }

    hfinal_kernel<<<dim3(256), blk, 0, stream>>>(
        H0h + (size_t)(T-1) * BH, H0l + (size_t)(T-1) * BH,
        H1h + (size_t)(T-1) * BH, H1l + (size_t)(T-1) * BH,
        out + (size_t)M * V);

    // logits = H1split @ Wy^T + by   (XCD-aware bijective block remap)
    gemm_mfma_swz<<<dim3(35 * 79), blk, 0, stream>>>(
        H1h, H1l, Wyh, Wyl, by, out, M, V, H);
}

// Round 15
// 1536.996 us; speedup vs baseline: 2.1400x; 2.1400x over previous
//
#include <hip/hip_runtime.h>
#include <hip/hip_bf16.h>
#include <cmath>
#include <cstdint>

// ---------------------------------------------------------------------------
// Stacked 2-layer Elman RNN, bf16 hi/lo-split MFMA (3-pass) everywhere.
//   fused split_all: all weights + initial hidden -> bf16 hi/lo (1 launch)
//   gather_split: emb[inputs] -> bf16 hi/lo
//   A0 = embsplit @ Wx0^T + bh0                         (MFMA GEMM)
//   ONE persistent cooperative kernel (128 blocks), flag-synced (R7/R12
//   scheme -- best measured passing):
//     blocks 0-63  (layer 0): h0[t] = tanh(A0[t] + h0[t-1] @ Wh0^T)
//     blocks 64-127(layer 1): h1[t] = tanh(h0[t]@Wx1^T + h1[t-1]@Wh1^T + bh1)
//     weight slices LDS-resident; h published as packed u64 agent-scope
//     relaxed atomic stores (write-through); counters fetch_add after
//     __syncthreads drain; relaxed polls.
//   h_final = hi+lo of t=69;
//   logits = H1split @ Wy^T + by  (separate GEMM, XCD-aware bijective remap)
// ---------------------------------------------------------------------------

using u16 = unsigned short;
using u32 = unsigned int;
using u64 = unsigned long long;
typedef __attribute__((ext_vector_type(8))) short short8;  // bf16x8 MFMA frag
typedef __attribute__((ext_vector_type(4))) float f32x4;

#define MFMA_BF16(a, b, c) __builtin_amdgcn_mfma_f32_16x16x32_bf16((a), (b), (c), 0, 0, 0)

__device__ __forceinline__ u16 bf16_rne(float x) {
    u32 u = __float_as_uint(x);
    u32 r = u + 0x7FFFu + ((u >> 16) & 1u);
    return (u16)(r >> 16);
}
__device__ __forceinline__ float bf16_f(u16 h) {
    return __uint_as_float(((u32)h) << 16);
}
__device__ __forceinline__ void split2(float x, u16& hi, u16& lo) {
    hi = bf16_rne(x);
    lo = bf16_rne(x - bf16_f(hi));
}
__device__ __forceinline__ u64 pack4(u16 a, u16 b, u16 c, u16 d) {
    return (u64)a | ((u64)b << 16) | ((u64)c << 32) | ((u64)d << 48);
}

// ---- cross-workgroup sync (R7 scheme: relaxed, no fences) -----------------
__device__ __forceinline__ void wait_count(int* f, int target) {
    if (threadIdx.x == 0) {
        while (__hip_atomic_load(f, __ATOMIC_RELAXED, __HIP_MEMORY_SCOPE_AGENT) < target)
            __builtin_amdgcn_s_sleep(1);
    }
    __syncthreads();
}
__device__ __forceinline__ void signal_done(int* f) {
    __syncthreads();   // vmcnt(0): write-through h-stores drained
    if (threadIdx.x == 0)
        __hip_atomic_fetch_add(f, 1, __ATOMIC_RELAXED, __HIP_MEMORY_SCOPE_AGENT);
}

// ---------------- fused split: six fp32 srcs -> bf16 hi/lo -----------------
// Segments (in float4 units): cumulative bounds precomputed on host side as
// constants here.  Layout matches the ws layout below.
struct SplitSeg { const float* src; u16* hi; u16* lo; int n4; };

__global__ __launch_bounds__(256) void split_all_kernel(
    const float* __restrict__ Wx0, u16* Wx0h, u16* Wx0l,
    const float* __restrict__ Wx1, u16* Wx1h, u16* Wx1l,
    const float* __restrict__ Wh0, u16* Wh0h, u16* Wh0l,
    const float* __restrict__ Wh1, u16* Wh1h, u16* Wh1l,
    const float* __restrict__ Wy,  u16* Wyh,  u16* Wyl,
    const float* __restrict__ hid, u16* hsh,  u16* hsl)
{
    // segment sizes in float4 units
    const int n0 = 131072;    // Wx0: 1024*512/4
    const int n1 = 262144;    // Wx1: 1024*1024/4
    const int n2 = 262144;    // Wh0
    const int n3 = 262144;    // Wh1
    const int n4s = 2560000;  // Wy: 10000*1024/4
    const int n5 = 32768;     // hidden: 2*64*1024/4
    int g = blockIdx.x * 256 + threadIdx.x;
    const float* src; u16* hi; u16* lo; int off;
    if      (g < n0)                       { src=Wx0; hi=Wx0h; lo=Wx0l; off=g; }
    else if ((g -= n0) < n1)               { src=Wx1; hi=Wx1h; lo=Wx1l; off=g; }
    else if ((g -= n1) < n2)               { src=Wh0; hi=Wh0h; lo=Wh0l; off=g; }
    else if ((g -= n2) < n3)               { src=Wh1; hi=Wh1h; lo=Wh1l; off=g; }
    else if ((g -= n3) < n4s)              { src=Wy;  hi=Wyh;  lo=Wyl;  off=g; }
    else if ((g -= n4s) < n5)              { src=hid; hi=hsh;  lo=hsl;  off=g; }
    else return;
    float4 v = *reinterpret_cast<const float4*>(src + (size_t)off * 4);
    u16 h0,h1,h2,h3,l0,l1,l2,l3;
    split2(v.x,h0,l0); split2(v.y,h1,l1); split2(v.z,h2,l2); split2(v.w,h3,l3);
    ushort4 H = {h0,h1,h2,h3}, L = {l0,l1,l2,l3};
    *reinterpret_cast<ushort4*>(hi + (size_t)off * 4) = H;
    *reinterpret_cast<ushort4*>(lo + (size_t)off * 4) = L;
}

// ---------------- fused gather(emb, idx) + split:  out [M][512] -------------
__global__ __launch_bounds__(256) void gather_split_kernel(
    const float* __restrict__ emb, const int* __restrict__ idx,
    u16* __restrict__ hi, u16* __restrict__ lo, int n4)
{
    int g = blockIdx.x * 256 + threadIdx.x;    // M*512/4 = 573440
    if (g >= n4) return;
    int m  = g >> 7;
    int c4 = g & 127;
    const float* src = emb + (size_t)idx[m] * 512 + c4 * 4;
    float4 v = *reinterpret_cast<const float4*>(src);
    u16 h0,h1,h2,h3,l0,l1,l2,l3;
    split2(v.x,h0,l0); split2(v.y,h1,l1); split2(v.z,h2,l2); split2(v.w,h3,l3);
    ushort4 H = {h0,h1,h2,h3}, L = {l0,l1,l2,l3};
    size_t o = (size_t)m * 512 + c4 * 4;
    *reinterpret_cast<ushort4*>(hi + o) = H;
    *reinterpret_cast<ushort4*>(lo + o) = L;
}

// ---------------- bf16-split MFMA GEMM tile body (device) ------------------
// C[m0:m0+128, n0:n0+128] = A @ B^T + bias for row-major A[M][K], B[N][K].
__device__ __forceinline__ void gemm_tile(
    const u16* __restrict__ Ah, const u16* __restrict__ Al,
    const u16* __restrict__ Bh, const u16* __restrict__ Bl,
    const float* __restrict__ bias, float* __restrict__ C,
    int N, int K, int m0, int n0,
    u16* sAh, u16* sAl, u16* sBh, u16* sBl)
{
    const int tid  = threadIdx.x;
    const int lane = tid & 63;
    const int w    = tid >> 6;
    const int wr   = w >> 1, wc = w & 1;

    f32x4 acc[4][4];
    #pragma unroll
    for (int i = 0; i < 4; ++i)
        #pragma unroll
        for (int j = 0; j < 4; ++j) acc[i][j] = 0.0f;

    for (int k0 = 0; k0 < K; k0 += 32) {
        #pragma unroll
        for (int r = 0; r < 2; ++r) {
            int s   = r * 256 + tid;
            int row = s >> 2, q = s & 3;
            int gq  = q ^ (row & 3);
            int l16 = row * 32 + q * 8;
            size_t ga = (size_t)(m0 + row) * K + k0 + gq * 8;
            int brow = n0 + row; if (brow >= N) brow = N - 1;
            size_t gb = (size_t)brow * K + k0 + gq * 8;
            *reinterpret_cast<int4*>(sAh + l16) = *reinterpret_cast<const int4*>(Ah + ga);
            *reinterpret_cast<int4*>(sAl + l16) = *reinterpret_cast<const int4*>(Al + ga);
            *reinterpret_cast<int4*>(sBh + l16) = *reinterpret_cast<const int4*>(Bh + gb);
            *reinterpret_cast<int4*>(sBl + l16) = *reinterpret_cast<const int4*>(Bl + gb);
        }
        __syncthreads();

        const int q4 = lane >> 4;
        short8 afh[4], afl[4];
        #pragma unroll
        for (int i = 0; i < 4; ++i) {
            int ra  = wr * 64 + i * 16 + (lane & 15);
            int off = ra * 32 + (q4 ^ (ra & 3)) * 8;
            afh[i] = *reinterpret_cast<const short8*>(sAh + off);
            afl[i] = *reinterpret_cast<const short8*>(sAl + off);
        }
        #pragma unroll
        for (int j = 0; j < 4; ++j) {
            int rb  = wc * 64 + j * 16 + (lane & 15);
            int off = rb * 32 + (q4 ^ (rb & 3)) * 8;
            short8 bfh = *reinterpret_cast<const short8*>(sBh + off);
            short8 bfl = *reinterpret_cast<const short8*>(sBl + off);
            #pragma unroll
            for (int i = 0; i < 4; ++i) {
                acc[i][j] = MFMA_BF16(afh[i], bfh, acc[i][j]);
                acc[i][j] = MFMA_BF16(afh[i], bfl, acc[i][j]);
                acc[i][j] = MFMA_BF16(afl[i], bfh, acc[i][j]);
            }
        }
        __syncthreads();
    }

    #pragma unroll
    for (int j = 0; j < 4; ++j) {
        int n = n0 + wc * 64 + j * 16 + (lane & 15);
        if (n < N) {
            float bv = bias[n];
            #pragma unroll
            for (int i = 0; i < 4; ++i) {
                #pragma unroll
                for (int r = 0; r < 4; ++r) {
                    int m = m0 + wr * 64 + i * 16 + (lane >> 4) * 4 + r;
                    C[(size_t)m * N + n] = acc[i][j][r] + bv;
                }
            }
        }
    }
}

// ---------------- standalone GEMM (A0 prologue) ----------------------------
__global__ __launch_bounds__(256) void gemm_mfma(
    const u16* __restrict__ Ah, const u16* __restrict__ Al,
    const u16* __restrict__ Bh, const u16* __restrict__ Bl,
    const float* __restrict__ bias, float* __restrict__ C,
    int M, int N, int K)
{
    __shared__ u16 sAh[128*32], sAl[128*32], sBh[128*32], sBl[128*32];
    gemm_tile(Ah, Al, Bh, Bl, bias, C, N, K,
              blockIdx.y * 128, blockIdx.x * 128, sAh, sAl, sBh, sBl);
}

// ---------------- logits GEMM with XCD-aware bijective block remap ---------
__global__ __launch_bounds__(256) void gemm_mfma_swz(
    const u16* __restrict__ Ah, const u16* __restrict__ Al,
    const u16* __restrict__ Bh, const u16* __restrict__ Bl,
    const float* __restrict__ bias, float* __restrict__ C,
    int M, int N, int K)
{
    __shared__ u16 sAh[128*32], sAl[128*32], sBh[128*32], sBl[128*32];
    const int NTN = 79;                       // ceil(10000/128)
    const int nwg = 35 * 79;                  // 2765
    const int q = nwg / 8, r = nwg % 8;       // 345, 5
    int orig = (int)blockIdx.x;
    int xcd  = orig % 8;
    int idx  = orig / 8;
    int wg   = (xcd < r) ? (xcd * (q + 1) + idx)
                         : (r * (q + 1) + (xcd - r) * q + idx);
    int mb = wg / NTN, nb = wg % NTN;
    gemm_tile(Ah, Al, Bh, Bl, bias, C, N, K,
              mb * 128, nb * 128, sAh, sAl, sBh, sBl);
}

// ---------------- persistent recurrence kernel (R12 exact) -----------------
// 128 blocks x 256 threads, cooperative (co-residency), NO grid.sync.
// flags[0..69]  = # layer-0 blocks done with h0[t]
// flags[70..139]= # layer-1 blocks done with h1[t]
__global__ __launch_bounds__(256, 1) void rnn_persist2(
    const float* __restrict__ A0,
    const u16* __restrict__ hs0h, const u16* __restrict__ hs0l,
    const u16* __restrict__ hs1h, const u16* __restrict__ hs1l,
    u16* __restrict__ H0h, u16* __restrict__ H0l,
    u16* __restrict__ H1h, u16* __restrict__ H1l,
    const u16* __restrict__ Wh0h, const u16* __restrict__ Wh0l,
    const u16* __restrict__ Wx1h, const u16* __restrict__ Wx1l,
    const u16* __restrict__ Wh1h, const u16* __restrict__ Wh1l,
    const float* __restrict__ bh1, int* flags)
{
    __shared__ u16 sW[65536];          // 128 KiB: [hi | lo] halves
    __shared__ float sStage[64 * 17];  // h-tile staging (pad 17 vs bank conflicts)
    const int tid   = threadIdx.x;
    const int lane  = tid & 63;
    const int w     = tid >> 6;
    const int layer = blockIdx.x >> 6;
    const int n0    = (int)(blockIdx.x & 63) * 16;
    const int m0    = w * 16;
    const int rb    = lane & 15;
    const int q4    = lane >> 4;
    const int arow  = m0 + rb;
    const size_t BH = 65536;
    const int srow  = tid >> 2;           // store phase: row 0..63
    const int sc4   = (tid & 3) * 4;      // store phase: col group

    // ---- stage weight slice into LDS, XOR-swizzled on 16B quads ----
    if (layer == 0) {
        for (int i = 0; i < 16; ++i) {
            int s    = i * 256 + tid;
            int arr  = s >> 11;
            int r    = (s >> 7) & 15;
            int g    = s & 127;
            int slot = g ^ (r & 7);
            const u16* src = (arr ? Wh0l : Wh0h) + (size_t)(n0 + r) * 1024 + g * 8;
            *reinterpret_cast<int4*>(sW + arr * 16384 + r * 1024 + slot * 8) =
                *reinterpret_cast<const int4*>(src);
        }
    } else {
        for (int i = 0; i < 32; ++i) {
            int s    = i * 256 + tid;
            int arr  = s >> 12;
            int r    = (s >> 8) & 15;
            int g    = s & 255;
            int slot = g ^ (r & 7);
            const u16* src;
            if (g < 128) src = (arr ? Wx1l : Wx1h) + (size_t)(n0 + r) * 1024 + g * 8;
            else         src = (arr ? Wh1l : Wh1h) + (size_t)(n0 + r) * 1024 + (g - 128) * 8;
            *reinterpret_cast<int4*>(sW + arr * 32768 + r * 2048 + slot * 8) =
                *reinterpret_cast<const int4*>(src);
        }
    }
    __syncthreads();

    if (layer == 0) {
        for (int t = 0; t < 70; ++t) {
            if (t > 0) wait_count(flags + (t - 1), 64);
            const u16* hph = t ? H0h + (size_t)(t - 1) * BH : hs0h;
            const u16* hpl = t ? H0l + (size_t)(t - 1) * BH : hs0l;
            f32x4 acc = {0.f, 0.f, 0.f, 0.f};
            #pragma unroll 8
            for (int kt = 0; kt < 32; ++kt) {
                short8 ah = *reinterpret_cast<const short8*>(hph + (size_t)arow * 1024 + kt * 32 + q4 * 8);
                short8 al = *reinterpret_cast<const short8*>(hpl + (size_t)arow * 1024 + kt * 32 + q4 * 8);
                int slot = (kt * 4 + q4) ^ (rb & 7);
                short8 bh = *reinterpret_cast<const short8*>(sW + rb * 1024 + slot * 8);
                short8 bl = *reinterpret_cast<const short8*>(sW + 16384 + rb * 1024 + slot * 8);
                acc = MFMA_BF16(ah, bh, acc);
                acc = MFMA_BF16(ah, bl, acc);
                acc = MFMA_BF16(al, bh, acc);
            }
            #pragma unroll
            for (int r = 0; r < 4; ++r) {
                int m = m0 + q4 * 4 + r;
                size_t o = (size_t)t * BH + (size_t)m * 1024 + n0 + rb;
                sStage[m * 17 + rb] = tanhf(acc[r] + A0[o]);
            }
            __syncthreads();
            {
                float f0 = sStage[srow * 17 + sc4 + 0];
                float f1 = sStage[srow * 17 + sc4 + 1];
                float f2 = sStage[srow * 17 + sc4 + 2];
                float f3 = sStage[srow * 17 + sc4 + 3];
                u16 a,b,c,d, la,lb,lc,ld;
                split2(f0,a,la); split2(f1,b,lb); split2(f2,c,lc); split2(f3,d,ld);
                size_t o64 = ((size_t)t * BH + (size_t)srow * 1024 + n0 + sc4) >> 2;
                __hip_atomic_store((u64*)H0h + o64, pack4(a,b,c,d),
                                   __ATOMIC_RELAXED, __HIP_MEMORY_SCOPE_AGENT);
                __hip_atomic_store((u64*)H0l + o64, pack4(la,lb,lc,ld),
                                   __ATOMIC_RELAXED, __HIP_MEMORY_SCOPE_AGENT);
            }
            signal_done(flags + t);
        }
    } else {
        for (int t = 0; t < 70; ++t) {
            wait_count(flags + t, 64);
            if (t > 0) wait_count(flags + 70 + (t - 1), 64);
            const u16* h0h  = H0h + (size_t)t * BH;
            const u16* h0l  = H0l + (size_t)t * BH;
            const u16* h1ph = t ? H1h + (size_t)(t - 1) * BH : hs1h;
            const u16* h1pl = t ? H1l + (size_t)(t - 1) * BH : hs1l;
            f32x4 acc = {0.f, 0.f, 0.f, 0.f};
            #pragma unroll 8
            for (int kt = 0; kt < 32; ++kt) {
                short8 ah = *reinterpret_cast<const short8*>(h0h + (size_t)arow * 1024 + kt * 32 + q4 * 8);
                short8 al = *reinterpret_cast<const short8*>(h0l + (size_t)arow * 1024 + kt * 32 + q4 * 8);
                int slot = (kt * 4 + q4) ^ (rb & 7);
                short8 bh = *reinterpret_cast<const short8*>(sW + rb * 2048 + slot * 8);
                short8 bl = *reinterpret_cast<const short8*>(sW + 32768 + rb * 2048 + slot * 8);
                acc = MFMA_BF16(ah, bh, acc);
                acc = MFMA_BF16(ah, bl, acc);
                acc = MFMA_BF16(al, bh, acc);
            }
            #pragma unroll 8
            for (int kt = 32; kt < 64; ++kt) {
                int ko = (kt - 32) * 32;
                short8 ah = *reinterpret_cast<const short8*>(h1ph + (size_t)arow * 1024 + ko + q4 * 8);
                short8 al = *reinterpret_cast<const short8*>(h1pl + (size_t)arow * 1024 + ko + q4 * 8);
                int slot = (kt * 4 + q4) ^ (rb & 7);
                short8 bh = *reinterpret_cast<const short8*>(sW + rb * 2048 + slot * 8);
                short8 bl = *reinterpret_cast<const short8*>(sW + 32768 + rb * 2048 + slot * 8);
                acc = MFMA_BF16(ah, bh, acc);
                acc = MFMA_BF16(ah, bl, acc);
                acc = MFMA_BF16(al, bh, acc);
            }
            const int n = n0 + rb;
            #pragma unroll
            for (int r = 0; r < 4; ++r) {
                int m = m0 + q4 * 4 + r;
                sStage[m * 17 + rb] = tanhf(acc[r] + bh1[n]);
            }
            __syncthreads();
            {
                float f0 = sStage[srow * 17 + sc4 + 0];
                float f1 = sStage[srow * 17 + sc4 + 1];
                float f2 = sStage[srow * 17 + sc4 + 2];
                float f3 = sStage[srow * 17 + sc4 + 3];
                u16 a,b,c,d, la,lb,lc,ld;
                split2(f0,a,la); split2(f1,b,lb); split2(f2,c,lc); split2(f3,d,ld);
                size_t o64 = ((size_t)t * BH + (size_t)srow * 1024 + n0 + sc4) >> 2;
                __hip_atomic_store((u64*)H1h + o64, pack4(a,b,c,d),
                                   __ATOMIC_RELAXED, __HIP_MEMORY_SCOPE_AGENT);
                __hip_atomic_store((u64*)H1l + o64, pack4(la,lb,lc,ld),
                                   __ATOMIC_RELAXED, __HIP_MEMORY_SCOPE_AGENT);
            }
            signal_done(flags + 70 + t);
        }
    }
}

// ---------------- h_final tail (hi+lo reconstruction) ----------------------
__global__ __launch_bounds__(256) void hfinal_kernel(
    const u16* __restrict__ H0h, const u16* __restrict__ H0l,
    const u16* __restrict__ H1h, const u16* __restrict__ H1l,
    float* __restrict__ outp)
{
    int i = blockIdx.x * 256 + threadIdx.x;
    outp[i]         = bf16_f(H0h[i]) + bf16_f(H0l[i]);
    outp[65536 + i] = bf16_f(H1h[i]) + bf16_f(H1l[i]);
}

extern "C" void kernel_launch(void* const* d_in, const int* in_sizes, int n_in,
                              void* d_out, int out_size, void* d_ws, size_t ws_size,
                              hipStream_t stream)
{
    const int*   inputs = (const int*)  d_in[0];
    const float* hidden = (const float*)d_in[1];
    const float* embW   = (const float*)d_in[2];
    const float* Wx0    = (const float*)d_in[3];
    const float* Wx1    = (const float*)d_in[4];
    const float* Wh0    = (const float*)d_in[5];
    const float* bh0    = (const float*)d_in[6];
    const float* Wh1    = (const float*)d_in[7];
    const float* bh1    = (const float*)d_in[8];
    const float* Wy     = (const float*)d_in[9];
    const float* by     = (const float*)d_in[10];
    float* out = (float*)d_out;

    const int T = 70, B = 64, V = 10000, E = 512, H = 1024;
    const int M = T * B;
    const size_t MH = (size_t)M * H;
    const size_t BH = (size_t)B * H;

    char* wsb = (char*)d_ws;
    u16*   Wyh  = (u16*)(wsb);
    u16*   Wyl  = Wyh + (size_t)V * H;
    float* buf0 = (float*)(wsb + 40960000);
    u16*   H0h  = (u16*)(wsb + 59310080);
    u16*   H0l  = H0h + MH;
    u16*   H1h  = H0l + MH;
    u16*   H1l  = H1h + MH;
    u16*   Wx0h = H1l + MH;
    u16*   Wx0l = Wx0h + (size_t)H * E;
    u16*   Wx1h = Wx0l + (size_t)H * E;
    u16*   Wx1l = Wx1h + (size_t)H * H;
    u16*   Wh0h = Wx1l + (size_t)H * H;
    u16*   Wh0l = Wh0h + (size_t)H * H;
    u16*   Wh1h = Wh0l + (size_t)H * H;
    u16*   Wh1l = Wh1h + (size_t)H * H;
    u16*   hs0h = Wh1l + (size_t)H * H;
    u16*   hs0l = hs0h + BH;
    u16*   hs1h = hs0l + BH;
    u16*   hs1l = hs1h + BH;

    // d_out aliased scratch: gathered emb splits (dead after A0 GEMM) and
    // sync flags (dead after persist; overwritten by logits afterwards).
    u16*   Agh   = (u16*)((char*)d_out + 20971520);
    u16*   Agl   = Agh + (size_t)M * E;
    int*   flags = (int*)((char*)d_out + 104857600);   // +100 MB, 140 ints

    dim3 blk(256);

    hipMemsetAsync(flags, 0, 140 * sizeof(int), stream);

    // fused splits: all weights + both hidden layers in one launch.
    // total float4 units = 131072+262144*3+2560000+32768 = 3510272 -> 13713 blocks
    split_all_kernel<<<dim3(13713), blk, 0, stream>>>(
        Wx0, Wx0h, Wx0l,
        Wx1, Wx1h, Wx1l,
        Wh0, Wh0h, Wh0l,
        Wh1, Wh1h, Wh1l,
        Wy,  Wyh,  Wyl,
        hidden, hs0h, hs0l);   // hidden covers both layers contiguously:
                               // hs0h/hs0l then hs1h/hs1l are contiguous in ws
    gather_split_kernel<<<dim3((M*E)/1024), blk, 0, stream>>>(embW, inputs, Agh, Agl, (M*E)/4);

    // A0 = embsplit @ Wx0^T + bh0
    gemm_mfma<<<dim3(H/128, M/128), blk, 0, stream>>>(
        Agh, Agl, Wx0h, Wx0l, bh0, buf0, M, H, E);

    // persistent recurrence, flag-synced (R12 exact)
    {
        const float* A0p = buf0;
        void* args[] = {
            (void*)&A0p,
            (void*)&hs0h, (void*)&hs0l, (void*)&hs1h, (void*)&hs1l,
            (void*)&H0h,  (void*)&H0l,  (void*)&H1h,  (void*)&H1l,
            (void*)&Wh0h, (void*)&Wh0l, (void*)&Wx1h, (void*)&Wx1l,
            (void*)&Wh1h, (void*)&Wh1l, (void*)&bh1, (void*)&flags
        };
        hipLaunchCooperativeKernel(reinterpret_cast<void*>(rnn_persist2),
                                   dim3(128), blk, args, 0, stream);
    }

    hfinal_kernel<<<dim3(256), blk, 0, stream>>>(
        H0h + (size_t)(T-1) * BH, H0l + (size_t)(T-1) * BH,
        H1h + (size_t)(T-1) * BH, H1l + (size_t)(T-1) * BH,
        out + (size_t)M * V);

    // logits = H1split @ Wy^T + by   (XCD-aware bijective block remap)
    gemm_mfma_swz<<<dim3(35 * 79), blk, 0, stream>>>(
        H1h, H1l, Wyh, Wyl, by, out, M, V, H);
}